// Round 16
// baseline (367.815 us; speedup 1.0000x reference)
//
#include <hip/hip_runtime.h>

#define CHUNK 2048

// Fused: embed blocks [0,embed_blocks) + per-chunk bucket histogram blocks.
__global__ __launch_bounds__(256) void embed_count_kernel(
    const int* __restrict__ x, const float* __restrict__ emb, float* __restrict__ h0,
    const int* __restrict__ ei, int* __restrict__ pcount,
    int n_nodes, int n_edges, int n_bkt, int embed_blocks)
{
    __shared__ int cnt[512];
    int t = threadIdx.x;
    if ((int)blockIdx.x < embed_blocks) {
        int tt = blockIdx.x * 256 + t;
        if (tt < n_nodes * 16) {
            int n = tt >> 4, q = tt & 15;
            int xv = x[n];
            float4 v = {0.f, 0.f, 0.f, 0.f};
            if (xv != 0) v = *(const float4*)(emb + (size_t)xv * 64 + q * 4);
            *(float4*)(h0 + (size_t)n * 64 + q * 4) = v;
        }
        return;
    }
    int jb = blockIdx.x - embed_blocks;
    for (int b = t; b < 512; b += 256) cnt[b] = 0;
    __syncthreads();
    int base = jb * CHUNK;
#pragma unroll
    for (int i = 0; i < CHUNK / 256; ++i) {
        int e = base + i * 256 + t;
        if (e < n_edges) atomicAdd(&cnt[ei[n_edges + e] >> 7], 1);
    }
    __syncthreads();
    for (int b = t; b < n_bkt; b += 256) pcount[jb * n_bkt + b] = cnt[b];
}

// blocks [0,n_bkt): exclusive scan over chunk counts -> pre, totals.
// blocks [n_bkt, n_bkt+ceil(G/256)): per-graph bounds -> inv_cnt[g],
// and out[g] initialized to linb (head bias; atomics accumulate on top).
__global__ __launch_bounds__(256) void colscan_kernel(
    const int* __restrict__ pcount, int* __restrict__ pre,
    int* __restrict__ totals, int* __restrict__ rowstartR,
    const int* __restrict__ batch, const float* __restrict__ linb,
    float* __restrict__ inv_cnt, float* __restrict__ outg,
    int n_chk, int n_bkt, int n_edges, int n_nodes, int n_graphs)
{
    __shared__ int ps[256];
    int b = blockIdx.x, t = threadIdx.x;
    if (b >= n_bkt) {
        int g = (b - n_bkt) * 256 + t;
        if (g < n_graphs) {
            int lo = 0, hi = n_nodes;
            while (lo < hi) { int mid = (lo + hi) >> 1; if (batch[mid] < g) lo = mid + 1; else hi = mid; }
            int s = lo;
            lo = 0; hi = n_nodes;
            while (lo < hi) { int mid = (lo + hi) >> 1; if (batch[mid] < g + 1) lo = mid + 1; else hi = mid; }
            inv_cnt[g] = 1.f / (float)max(lo - s, 1);
            outg[2 * g + 0] = linb[0];
            outg[2 * g + 1] = linb[1];
        }
        return;
    }
    if (b == 0 && t == 0) rowstartR[4 * n_nodes] = n_edges;
    int v[4], s = 0;
#pragma unroll
    for (int i = 0; i < 4; ++i) {
        int jj = t * 4 + i;
        v[i] = (jj < n_chk) ? pcount[jj * n_bkt + b] : 0;
        s += v[i];
    }
    ps[t] = s;
    __syncthreads();
    for (int o = 1; o < 256; o <<= 1) {
        int u = (t >= o) ? ps[t - o] : 0;
        __syncthreads();
        ps[t] += u;
        __syncthreads();
    }
    int run = (t > 0) ? ps[t - 1] : 0;
#pragma unroll
    for (int i = 0; i < 4; ++i) {
        int jj = t * 4 + i;
        if (jj < n_chk) pre[jj * n_bkt + b] = run;
        run += v[i];
    }
    if (t == 255) totals[b] = run;
}

// 611 blocks x 2048 edges; deterministic bases (local scan of totals + pre row),
// LDS fill atomics only. Block 0 publishes bucket_start for the sort.
__global__ __launch_bounds__(256) void scatter_kernel(
    const int* __restrict__ ei, const int* __restrict__ et,
    const int* __restrict__ pre, const int* __restrict__ totals,
    int* __restrict__ esort, int* __restrict__ bucket_start,
    int n_edges, int n_bkt)
{
    __shared__ int bs[512], fill2[512], ps[256];
    int t = threadIdx.x, j = blockIdx.x;
    int a0 = (2 * t < n_bkt) ? totals[2 * t] : 0;
    int a1 = (2 * t + 1 < n_bkt) ? totals[2 * t + 1] : 0;
    ps[t] = a0 + a1;
    __syncthreads();
    for (int o = 1; o < 256; o <<= 1) {
        int u = (t >= o) ? ps[t - o] : 0;
        __syncthreads();
        ps[t] += u;
        __syncthreads();
    }
    int basex = (t > 0) ? ps[t - 1] : 0;
    bs[2 * t] = basex;
    bs[2 * t + 1] = basex + a0;
    fill2[t] = 0; fill2[t + 256] = 0;
    __syncthreads();
    if (j == 0) {
        for (int b = t; b < n_bkt; b += 256) bucket_start[b] = bs[b];
        if (t == 0) bucket_start[n_bkt] = n_edges;
    }
    for (int b = t; b < n_bkt; b += 256) bs[b] += pre[j * n_bkt + b];
    __syncthreads();
    int base = j * CHUNK;
#pragma unroll
    for (int i = 0; i < CHUNK / 256; ++i) {
        int e = base + i * 256 + t;
        if (e < n_edges) {
            int s = ei[e], d = ei[n_edges + e], r = et[e];
            int b = d >> 7;
            int pos = bs[b] + atomicAdd(&fill2[b], 1);
            esort[pos] = s | (r << 16) | ((d & 127) << 18);
        }
    }
}

// one block per bucket: 512-bin counting sort (bin = dstlo*4 + r),
// emits rowstartR[dst*4 + r].
__global__ __launch_bounds__(256) void bucket_sort_kernel(
    const int* __restrict__ bucket_start, int* __restrict__ esort,
    int* __restrict__ scratch, int* __restrict__ rowstartR, int n_nodes)
{
    __shared__ int cnt[512], off[512], fill[512], ps[256];
    int t = threadIdx.x, b = blockIdx.x;
    int s = bucket_start[b], e = bucket_start[b + 1];
    cnt[t] = 0; cnt[t + 256] = 0; fill[t] = 0; fill[t + 256] = 0;
    __syncthreads();
    int* scr = scratch + (size_t)b * 8192;
    for (int i = s + t; i < e; i += 256) {
        int p = esort[i];
        scr[i - s] = p;
        atomicAdd(&cnt[(p >> 16) & 0x1FF], 1);
    }
    __syncthreads();
    int a0 = cnt[2 * t], a1 = cnt[2 * t + 1];
    ps[t] = a0 + a1;
    __syncthreads();
    for (int o = 1; o < 256; o <<= 1) {
        int v = (t >= o) ? ps[t - o] : 0;
        __syncthreads();
        ps[t] += v;
        __syncthreads();
    }
    int basex = (t > 0) ? ps[t - 1] : 0;
    off[2 * t] = basex;
    off[2 * t + 1] = basex + a0;
    __syncthreads();
    int d0 = b * 128 + (2 * t >> 2);
    if (d0 < n_nodes) rowstartR[b * 512 + 2 * t] = s + off[2 * t];
    int d1 = b * 128 + ((2 * t + 1) >> 2);
    if (d1 < n_nodes) rowstartR[b * 512 + 2 * t + 1] = s + off[2 * t + 1];
    __syncthreads();
    for (int i = s + t; i < e; i += 256) {
        int p = scr[i - s];
        int bin = (p >> 16) & 0x1FF;
        int pos = s + off[bin] + atomicAdd(&fill[bin], 1);
        esort[pos] = p;
    }
}

// one wave per dst. Masked full-row MLP: quarter q takes a 4-edge window per
// 16-stride over the whole row; 4 independent row-loads in flight.
__global__ __launch_bounds__(256) void agg_kernel(
    const float* __restrict__ hin, const int* __restrict__ rowstartR,
    const int* __restrict__ esort, float* __restrict__ means, int n_nodes)
{
    int wid = (blockIdx.x * 256 + threadIdx.x) >> 6;
    int lane = threadIdx.x & 63;
    if (wid >= n_nodes) return;
    int q = lane >> 4;
    int c = lane & 15;
    int4 rs = *(const int4*)(rowstartR + wid * 4);
    int s = rs.x, e = rs.w;

    float4 a0 = {0.f,0.f,0.f,0.f}, a1 = {0.f,0.f,0.f,0.f}, a2 = {0.f,0.f,0.f,0.f};

    int i = s + 4 * q;
    for (; i + 4 <= e; i += 16) {
        int p0 = esort[i], p1 = esort[i + 1], p2 = esort[i + 2], p3 = esort[i + 3];
        float4 v0 = *(const float4*)(hin + (size_t)(p0 & 0xFFFF) * 64 + c * 4);
        float4 v1 = *(const float4*)(hin + (size_t)(p1 & 0xFFFF) * 64 + c * 4);
        float4 v2 = *(const float4*)(hin + (size_t)(p2 & 0xFFFF) * 64 + c * 4);
        float4 v3 = *(const float4*)(hin + (size_t)(p3 & 0xFFFF) * 64 + c * 4);
#pragma unroll
        for (int m = 0; m < 4; ++m) {
            int p = m == 0 ? p0 : m == 1 ? p1 : m == 2 ? p2 : p3;
            float4 v = m == 0 ? v0 : m == 1 ? v1 : m == 2 ? v2 : v3;
            int r = (p >> 16) & 3;
            float m0 = (r == 0) ? 1.f : 0.f;
            float m1 = (r == 1) ? 1.f : 0.f;
            float m2 = (r == 2) ? 1.f : 0.f;
            a0.x = fmaf(m0, v.x, a0.x); a0.y = fmaf(m0, v.y, a0.y);
            a0.z = fmaf(m0, v.z, a0.z); a0.w = fmaf(m0, v.w, a0.w);
            a1.x = fmaf(m1, v.x, a1.x); a1.y = fmaf(m1, v.y, a1.y);
            a1.z = fmaf(m1, v.z, a1.z); a1.w = fmaf(m1, v.w, a1.w);
            a2.x = fmaf(m2, v.x, a2.x); a2.y = fmaf(m2, v.y, a2.y);
            a2.z = fmaf(m2, v.z, a2.z); a2.w = fmaf(m2, v.w, a2.w);
        }
    }
#pragma unroll
    for (int m = 0; m < 3; ++m) {
        int ii = i + m;
        if (ii < e) {
            int p = esort[ii];
            float4 v = *(const float4*)(hin + (size_t)(p & 0xFFFF) * 64 + c * 4);
            int r = (p >> 16) & 3;
            float m0 = (r == 0) ? 1.f : 0.f;
            float m1 = (r == 1) ? 1.f : 0.f;
            float m2 = (r == 2) ? 1.f : 0.f;
            a0.x = fmaf(m0, v.x, a0.x); a0.y = fmaf(m0, v.y, a0.y);
            a0.z = fmaf(m0, v.z, a0.z); a0.w = fmaf(m0, v.w, a0.w);
            a1.x = fmaf(m1, v.x, a1.x); a1.y = fmaf(m1, v.y, a1.y);
            a1.z = fmaf(m1, v.z, a1.z); a1.w = fmaf(m1, v.w, a1.w);
            a2.x = fmaf(m2, v.x, a2.x); a2.y = fmaf(m2, v.y, a2.y);
            a2.z = fmaf(m2, v.z, a2.z); a2.w = fmaf(m2, v.w, a2.w);
        }
    }
#pragma unroll
    for (int off = 16; off < 64; off <<= 1) {
        a0.x += __shfl_xor(a0.x, off); a0.y += __shfl_xor(a0.y, off);
        a0.z += __shfl_xor(a0.z, off); a0.w += __shfl_xor(a0.w, off);
        a1.x += __shfl_xor(a1.x, off); a1.y += __shfl_xor(a1.y, off);
        a1.z += __shfl_xor(a1.z, off); a1.w += __shfl_xor(a1.w, off);
        a2.x += __shfl_xor(a2.x, off); a2.y += __shfl_xor(a2.y, off);
        a2.z += __shfl_xor(a2.z, off); a2.w += __shfl_xor(a2.w, off);
    }
    if (q < 3) {
        int cnt = (q == 0) ? (rs.y - rs.x) : (q == 1) ? (rs.z - rs.y) : (rs.w - rs.z);
        float4 a = (q == 0) ? a0 : (q == 1) ? a1 : a2;
        float inv = 1.f / (float)max(cnt, 1);
        float4 m = {a.x * inv, a.y * inv, a.z * inv, a.w * inv};
        *(float4*)(means + (size_t)wid * 192 + q * 64 + c * 4) = m;
    }
}

// thread = (4-node group, j-quad). W streamed through LDS in 4 slabs of 64
// rows, double-buffered (32 KB). do_pool=1 (layer 2): skip hout stores and
// instead reduce the relu'd rows against linw (16-lane shuffle) and
// atomicAdd per-node head contributions scaled by inv_cnt[batch[n]].
__global__ __launch_bounds__(256) void transform_kernel(
    const float* __restrict__ hin, const float* __restrict__ means,
    const float* __restrict__ wroot, const float* __restrict__ wrel,
    const float* __restrict__ bias, float* __restrict__ hout,
    const int* __restrict__ batch, const float* __restrict__ linw,
    const float* __restrict__ inv_cnt, float* __restrict__ outg,
    int n_nodes, int do_pool)
{
    __shared__ float wsh[2][4096];   // 2 x 16 KB
    int t = threadIdx.x;
    int gt = blockIdx.x * 256 + t;
    int g = gt >> 4, q = gt & 15;
    int n0 = g * 4;
    bool active = (n0 < n_nodes);

    {
        const float4* sp = (const float4*)wroot;
        float4* d = (float4*)wsh[0];
#pragma unroll
        for (int i = 0; i < 4; ++i) d[t + i * 256] = sp[t + i * 256];
    }

    float4 acc[4];
    float4 b = {0.f, 0.f, 0.f, 0.f};
    if (active) b = *(const float4*)(bias + q * 4);
#pragma unroll
    for (int i = 0; i < 4; ++i) acc[i] = b;

    const float* hv = hin + (size_t)n0 * 64;
    const float* mv = means + (size_t)n0 * 192;

    for (int s = 0; s < 4; ++s) {
        __syncthreads();
        if (s < 3) {
            const float4* sp = (const float4*)wrel + (size_t)s * 1024;
            float4* d = (float4*)wsh[(s + 1) & 1];
#pragma unroll
            for (int i = 0; i < 4; ++i) d[t + i * 256] = sp[t + i * 256];
        }
        const float* vbase = (s == 0) ? hv : (mv + (s - 1) * 64);
        int vstride = (s == 0) ? 64 : 192;
        const float* wbuf = wsh[s & 1];
        if (active) {
#pragma unroll 4
            for (int k4 = 0; k4 < 16; ++k4) {
                float4 v[4];
#pragma unroll
                for (int i = 0; i < 4; ++i)
                    v[i] = *(const float4*)(vbase + i * vstride + k4 * 4);
#pragma unroll
                for (int kk = 0; kk < 4; ++kk) {
                    float4 w = *(const float4*)(wbuf + (k4 * 4 + kk) * 64 + q * 4);
#pragma unroll
                    for (int i = 0; i < 4; ++i) {
                        float sv = kk == 0 ? v[i].x : kk == 1 ? v[i].y : kk == 2 ? v[i].z : v[i].w;
                        acc[i].x = fmaf(sv, w.x, acc[i].x);
                        acc[i].y = fmaf(sv, w.y, acc[i].y);
                        acc[i].z = fmaf(sv, w.z, acc[i].z);
                        acc[i].w = fmaf(sv, w.w, acc[i].w);
                    }
                }
            }
        }
    }
    if (!do_pool) {
        if (active) {
            float* o = hout + (size_t)n0 * 64 + q * 4;
#pragma unroll
            for (int i = 0; i < 4; ++i) {
                float4 r = {fmaxf(acc[i].x, 0.f), fmaxf(acc[i].y, 0.f),
                            fmaxf(acc[i].z, 0.f), fmaxf(acc[i].w, 0.f)};
                *(float4*)(o + i * 64) = r;
            }
        }
    } else if (active) {
        // head: per node, d = relu(row) @ linw[64][2] restricted to channels q*4..q*4+3
        float4 lwA = *(const float4*)(linw + q * 8);       // (c0w0,c0w1,c1w0,c1w1)
        float4 lwB = *(const float4*)(linw + q * 8 + 4);   // (c2w0,c2w1,c3w0,c3w1)
        float d0[4], d1[4];
#pragma unroll
        for (int i = 0; i < 4; ++i) {
            float4 r = {fmaxf(acc[i].x, 0.f), fmaxf(acc[i].y, 0.f),
                        fmaxf(acc[i].z, 0.f), fmaxf(acc[i].w, 0.f)};
            d0[i] = r.x * lwA.x + r.y * lwA.z + r.z * lwB.x + r.w * lwB.z;
            d1[i] = r.x * lwA.y + r.y * lwA.w + r.z * lwB.y + r.w * lwB.w;
        }
#pragma unroll
        for (int off = 1; off < 16; off <<= 1) {
#pragma unroll
            for (int i = 0; i < 4; ++i) {
                d0[i] += __shfl_xor(d0[i], off);
                d1[i] += __shfl_xor(d1[i], off);
            }
        }
        if (q == 0) {
#pragma unroll
            for (int i = 0; i < 4; ++i) {
                int n = n0 + i;
                if (n < n_nodes) {
                    int gg = batch[n];
                    float ic = inv_cnt[gg];
                    atomicAdd(&outg[2 * gg + 0], d0[i] * ic);
                    atomicAdd(&outg[2 * gg + 1], d1[i] * ic);
                }
            }
        }
    }
}

extern "C" void kernel_launch(void* const* d_in, const int* in_sizes, int n_in,
                              void* d_out, int out_size, void* d_ws, size_t ws_size,
                              hipStream_t stream)
{
    const int*   x      = (const int*)d_in[0];
    const int*   ei     = (const int*)d_in[1];
    const int*   et     = (const int*)d_in[2];
    const int*   batch  = (const int*)d_in[3];
    const float* emb    = (const float*)d_in[4];
    const float* w1rel  = (const float*)d_in[5];
    const float* w1root = (const float*)d_in[6];
    const float* b1     = (const float*)d_in[7];
    const float* w2rel  = (const float*)d_in[8];
    const float* w2root = (const float*)d_in[9];
    const float* b2     = (const float*)d_in[10];
    const float* linw   = (const float*)d_in[11];
    const float* linb   = (const float*)d_in[12];
    float* out = (float*)d_out;

    const int N = in_sizes[0];            // 50000
    const int E = in_sizes[2];            // 1250000
    const int G = out_size / 2;           // 512
    const int NBKT = (N + 127) >> 7;      // 391
    const int NCHK = (E + CHUNK - 1) / CHUNK;  // 611

    float* hA        = (float*)d_ws;                     // [N][64]
    float* hB        = hA + (size_t)N * 64;              // [N][64]
    float* means     = hB + (size_t)N * 64;              // [N][192]
    int*   esort     = (int*)(means + (size_t)N * 192);  // [E]
    int*   rowstartR = esort + E;                        // [4N+4]
    int*   bucket_start = rowstartR + 4 * N + 4;         // [NBKT+1]
    int*   totals    = bucket_start + NBKT + 1;          // [NBKT]
    float* inv_cnt   = (float*)(totals + NBKT);          // [G]
    int*   scratch   = (int*)means;                      // sort scratch (12.8 MB)
    int*   pcount    = (int*)means + 4 * 1024 * 1024;    // [NCHK*NBKT]
    int*   pre       = (int*)means + 5 * 1024 * 1024;    // [NCHK*NBKT]

    int embedBlocks = (N * 16 + 255) / 256;              // 3125
    embed_count_kernel<<<embedBlocks + NCHK, 256, 0, stream>>>(
        x, emb, hA, ei, pcount, N, E, NBKT, embedBlocks);
    int gBlocks = (G + 255) / 256;                       // graph-bounds tail blocks
    colscan_kernel<<<NBKT + gBlocks, 256, 0, stream>>>(
        pcount, pre, totals, rowstartR, batch, linb, inv_cnt, out,
        NCHK, NBKT, E, N, G);
    scatter_kernel<<<NCHK, 256, 0, stream>>>(ei, et, pre, totals, esort, bucket_start, E, NBKT);
    bucket_sort_kernel<<<NBKT, 256, 0, stream>>>(bucket_start, esort, scratch, rowstartR, N);

    int aggBlocks = (N * 64 + 255) / 256;                // one wave per dst
    int tfBlocks  = ((N + 3) / 4 * 16 + 255) / 256;      // 4 nodes per thread
    agg_kernel<<<aggBlocks, 256, 0, stream>>>(hA, rowstartR, esort, means, N);
    transform_kernel<<<tfBlocks, 256, 0, stream>>>(
        hA, means, w1root, w1rel, b1, hB, batch, linw, inv_cnt, out, N, 0);
    agg_kernel<<<aggBlocks, 256, 0, stream>>>(hB, rowstartR, esort, means, N);
    transform_kernel<<<tfBlocks, 256, 0, stream>>>(
        hB, means, w2root, w2rel, b2, hA, batch, linw, inv_cnt, out, N, 1);
}

// Round 17
// 309.224 us; speedup vs baseline: 1.1895x; 1.1895x over previous
//
#include <hip/hip_runtime.h>

#define CHUNK 2048

// Fused: embed blocks [0,embed_blocks) + per-chunk bucket histogram blocks.
__global__ __launch_bounds__(256) void embed_count_kernel(
    const int* __restrict__ x, const float* __restrict__ emb, float* __restrict__ h0,
    const int* __restrict__ ei, int* __restrict__ pcount,
    int n_nodes, int n_edges, int n_bkt, int embed_blocks)
{
    __shared__ int cnt[512];
    int t = threadIdx.x;
    if ((int)blockIdx.x < embed_blocks) {
        int tt = blockIdx.x * 256 + t;
        if (tt < n_nodes * 16) {
            int n = tt >> 4, q = tt & 15;
            int xv = x[n];
            float4 v = {0.f, 0.f, 0.f, 0.f};
            if (xv != 0) v = *(const float4*)(emb + (size_t)xv * 64 + q * 4);
            *(float4*)(h0 + (size_t)n * 64 + q * 4) = v;
        }
        return;
    }
    int jb = blockIdx.x - embed_blocks;
    for (int b = t; b < 512; b += 256) cnt[b] = 0;
    __syncthreads();
    int base = jb * CHUNK;
#pragma unroll
    for (int i = 0; i < CHUNK / 256; ++i) {
        int e = base + i * 256 + t;
        if (e < n_edges) atomicAdd(&cnt[ei[n_edges + e] >> 7], 1);
    }
    __syncthreads();
    for (int b = t; b < n_bkt; b += 256) pcount[jb * n_bkt + b] = cnt[b];
}

// blocks [0,n_bkt): exclusive scan over chunk counts -> pre, totals.
// blocks [n_bkt, ...): per-graph bounds -> inv_cnt[g]; out[g] init to linb.
__global__ __launch_bounds__(256) void colscan_kernel(
    const int* __restrict__ pcount, int* __restrict__ pre,
    int* __restrict__ totals, int* __restrict__ rowstartR,
    const int* __restrict__ batch, const float* __restrict__ linb,
    float* __restrict__ inv_cnt, float* __restrict__ outg,
    int n_chk, int n_bkt, int n_edges, int n_nodes, int n_graphs)
{
    __shared__ int ps[256];
    int b = blockIdx.x, t = threadIdx.x;
    if (b >= n_bkt) {
        int g = (b - n_bkt) * 256 + t;
        if (g < n_graphs) {
            int lo = 0, hi = n_nodes;
            while (lo < hi) { int mid = (lo + hi) >> 1; if (batch[mid] < g) lo = mid + 1; else hi = mid; }
            int s = lo;
            lo = 0; hi = n_nodes;
            while (lo < hi) { int mid = (lo + hi) >> 1; if (batch[mid] < g + 1) lo = mid + 1; else hi = mid; }
            inv_cnt[g] = 1.f / (float)max(lo - s, 1);
            outg[2 * g + 0] = linb[0];
            outg[2 * g + 1] = linb[1];
        }
        return;
    }
    if (b == 0 && t == 0) rowstartR[4 * n_nodes] = n_edges;
    int v[4], s = 0;
#pragma unroll
    for (int i = 0; i < 4; ++i) {
        int jj = t * 4 + i;
        v[i] = (jj < n_chk) ? pcount[jj * n_bkt + b] : 0;
        s += v[i];
    }
    ps[t] = s;
    __syncthreads();
    for (int o = 1; o < 256; o <<= 1) {
        int u = (t >= o) ? ps[t - o] : 0;
        __syncthreads();
        ps[t] += u;
        __syncthreads();
    }
    int run = (t > 0) ? ps[t - 1] : 0;
#pragma unroll
    for (int i = 0; i < 4; ++i) {
        int jj = t * 4 + i;
        if (jj < n_chk) pre[jj * n_bkt + b] = run;
        run += v[i];
    }
    if (t == 255) totals[b] = run;
}

// 611 blocks x 2048 edges; deterministic bases (local scan of totals + pre row),
// LDS fill atomics only. Block 0 publishes bucket_start for the sort.
__global__ __launch_bounds__(256) void scatter_kernel(
    const int* __restrict__ ei, const int* __restrict__ et,
    const int* __restrict__ pre, const int* __restrict__ totals,
    int* __restrict__ esort, int* __restrict__ bucket_start,
    int n_edges, int n_bkt)
{
    __shared__ int bs[512], fill2[512], ps[256];
    int t = threadIdx.x, j = blockIdx.x;
    int a0 = (2 * t < n_bkt) ? totals[2 * t] : 0;
    int a1 = (2 * t + 1 < n_bkt) ? totals[2 * t + 1] : 0;
    ps[t] = a0 + a1;
    __syncthreads();
    for (int o = 1; o < 256; o <<= 1) {
        int u = (t >= o) ? ps[t - o] : 0;
        __syncthreads();
        ps[t] += u;
        __syncthreads();
    }
    int basex = (t > 0) ? ps[t - 1] : 0;
    bs[2 * t] = basex;
    bs[2 * t + 1] = basex + a0;
    fill2[t] = 0; fill2[t + 256] = 0;
    __syncthreads();
    if (j == 0) {
        for (int b = t; b < n_bkt; b += 256) bucket_start[b] = bs[b];
        if (t == 0) bucket_start[n_bkt] = n_edges;
    }
    for (int b = t; b < n_bkt; b += 256) bs[b] += pre[j * n_bkt + b];
    __syncthreads();
    int base = j * CHUNK;
#pragma unroll
    for (int i = 0; i < CHUNK / 256; ++i) {
        int e = base + i * 256 + t;
        if (e < n_edges) {
            int s = ei[e], d = ei[n_edges + e], r = et[e];
            int b = d >> 7;
            int pos = bs[b] + atomicAdd(&fill2[b], 1);
            esort[pos] = s | (r << 16) | ((d & 127) << 18);
        }
    }
}

// one block per bucket: 512-bin counting sort (bin = dstlo*4 + r),
// emits rowstartR[dst*4 + r].
__global__ __launch_bounds__(256) void bucket_sort_kernel(
    const int* __restrict__ bucket_start, int* __restrict__ esort,
    int* __restrict__ scratch, int* __restrict__ rowstartR, int n_nodes)
{
    __shared__ int cnt[512], off[512], fill[512], ps[256];
    int t = threadIdx.x, b = blockIdx.x;
    int s = bucket_start[b], e = bucket_start[b + 1];
    cnt[t] = 0; cnt[t + 256] = 0; fill[t] = 0; fill[t + 256] = 0;
    __syncthreads();
    int* scr = scratch + (size_t)b * 8192;
    for (int i = s + t; i < e; i += 256) {
        int p = esort[i];
        scr[i - s] = p;
        atomicAdd(&cnt[(p >> 16) & 0x1FF], 1);
    }
    __syncthreads();
    int a0 = cnt[2 * t], a1 = cnt[2 * t + 1];
    ps[t] = a0 + a1;
    __syncthreads();
    for (int o = 1; o < 256; o <<= 1) {
        int v = (t >= o) ? ps[t - o] : 0;
        __syncthreads();
        ps[t] += v;
        __syncthreads();
    }
    int basex = (t > 0) ? ps[t - 1] : 0;
    off[2 * t] = basex;
    off[2 * t + 1] = basex + a0;
    __syncthreads();
    int d0 = b * 128 + (2 * t >> 2);
    if (d0 < n_nodes) rowstartR[b * 512 + 2 * t] = s + off[2 * t];
    int d1 = b * 128 + ((2 * t + 1) >> 2);
    if (d1 < n_nodes) rowstartR[b * 512 + 2 * t + 1] = s + off[2 * t + 1];
    __syncthreads();
    for (int i = s + t; i < e; i += 256) {
        int p = scr[i - s];
        int bin = (p >> 16) & 0x1FF;
        int pos = s + off[bin] + atomicAdd(&fill[bin], 1);
        esort[pos] = p;
    }
}

// one wave per dst. Masked full-row MLP: quarter q takes a 4-edge window per
// 16-stride over the whole row; 4 independent row-loads in flight.
__global__ __launch_bounds__(256) void agg_kernel(
    const float* __restrict__ hin, const int* __restrict__ rowstartR,
    const int* __restrict__ esort, float* __restrict__ means, int n_nodes)
{
    int wid = (blockIdx.x * 256 + threadIdx.x) >> 6;
    int lane = threadIdx.x & 63;
    if (wid >= n_nodes) return;
    int q = lane >> 4;
    int c = lane & 15;
    int4 rs = *(const int4*)(rowstartR + wid * 4);
    int s = rs.x, e = rs.w;

    float4 a0 = {0.f,0.f,0.f,0.f}, a1 = {0.f,0.f,0.f,0.f}, a2 = {0.f,0.f,0.f,0.f};

    int i = s + 4 * q;
    for (; i + 4 <= e; i += 16) {
        int p0 = esort[i], p1 = esort[i + 1], p2 = esort[i + 2], p3 = esort[i + 3];
        float4 v0 = *(const float4*)(hin + (size_t)(p0 & 0xFFFF) * 64 + c * 4);
        float4 v1 = *(const float4*)(hin + (size_t)(p1 & 0xFFFF) * 64 + c * 4);
        float4 v2 = *(const float4*)(hin + (size_t)(p2 & 0xFFFF) * 64 + c * 4);
        float4 v3 = *(const float4*)(hin + (size_t)(p3 & 0xFFFF) * 64 + c * 4);
#pragma unroll
        for (int m = 0; m < 4; ++m) {
            int p = m == 0 ? p0 : m == 1 ? p1 : m == 2 ? p2 : p3;
            float4 v = m == 0 ? v0 : m == 1 ? v1 : m == 2 ? v2 : v3;
            int r = (p >> 16) & 3;
            float m0 = (r == 0) ? 1.f : 0.f;
            float m1 = (r == 1) ? 1.f : 0.f;
            float m2 = (r == 2) ? 1.f : 0.f;
            a0.x = fmaf(m0, v.x, a0.x); a0.y = fmaf(m0, v.y, a0.y);
            a0.z = fmaf(m0, v.z, a0.z); a0.w = fmaf(m0, v.w, a0.w);
            a1.x = fmaf(m1, v.x, a1.x); a1.y = fmaf(m1, v.y, a1.y);
            a1.z = fmaf(m1, v.z, a1.z); a1.w = fmaf(m1, v.w, a1.w);
            a2.x = fmaf(m2, v.x, a2.x); a2.y = fmaf(m2, v.y, a2.y);
            a2.z = fmaf(m2, v.z, a2.z); a2.w = fmaf(m2, v.w, a2.w);
        }
    }
#pragma unroll
    for (int m = 0; m < 3; ++m) {
        int ii = i + m;
        if (ii < e) {
            int p = esort[ii];
            float4 v = *(const float4*)(hin + (size_t)(p & 0xFFFF) * 64 + c * 4);
            int r = (p >> 16) & 3;
            float m0 = (r == 0) ? 1.f : 0.f;
            float m1 = (r == 1) ? 1.f : 0.f;
            float m2 = (r == 2) ? 1.f : 0.f;
            a0.x = fmaf(m0, v.x, a0.x); a0.y = fmaf(m0, v.y, a0.y);
            a0.z = fmaf(m0, v.z, a0.z); a0.w = fmaf(m0, v.w, a0.w);
            a1.x = fmaf(m1, v.x, a1.x); a1.y = fmaf(m1, v.y, a1.y);
            a1.z = fmaf(m1, v.z, a1.z); a1.w = fmaf(m1, v.w, a1.w);
            a2.x = fmaf(m2, v.x, a2.x); a2.y = fmaf(m2, v.y, a2.y);
            a2.z = fmaf(m2, v.z, a2.z); a2.w = fmaf(m2, v.w, a2.w);
        }
    }
#pragma unroll
    for (int off = 16; off < 64; off <<= 1) {
        a0.x += __shfl_xor(a0.x, off); a0.y += __shfl_xor(a0.y, off);
        a0.z += __shfl_xor(a0.z, off); a0.w += __shfl_xor(a0.w, off);
        a1.x += __shfl_xor(a1.x, off); a1.y += __shfl_xor(a1.y, off);
        a1.z += __shfl_xor(a1.z, off); a1.w += __shfl_xor(a1.w, off);
        a2.x += __shfl_xor(a2.x, off); a2.y += __shfl_xor(a2.y, off);
        a2.z += __shfl_xor(a2.z, off); a2.w += __shfl_xor(a2.w, off);
    }
    if (q < 3) {
        int cnt = (q == 0) ? (rs.y - rs.x) : (q == 1) ? (rs.z - rs.y) : (rs.w - rs.z);
        float4 a = (q == 0) ? a0 : (q == 1) ? a1 : a2;
        float inv = 1.f / (float)max(cnt, 1);
        float4 m = {a.x * inv, a.y * inv, a.z * inv, a.w * inv};
        *(float4*)(means + (size_t)wid * 192 + q * 64 + c * 4) = m;
    }
}

// thread = (4-node group, j-quad). W streamed through LDS in 4 slabs of 64
// rows, double-buffered (32 KB). do_pool=1 (layer 2): skip hout stores; head
// contributions are LDS-aggregated PER BLOCK (block covers 64 consecutive
// nodes spanning <=64 graphs) then flushed with ~2-3 global atomics/block —
// R16's per-node atomics (100K onto 64 lines, cross-XCD serialized) cost
// +60 us; this cuts global atomics ~50x.
__global__ __launch_bounds__(256) void transform_kernel(
    const float* __restrict__ hin, const float* __restrict__ means,
    const float* __restrict__ wroot, const float* __restrict__ wrel,
    const float* __restrict__ bias, float* __restrict__ hout,
    const int* __restrict__ batch, const float* __restrict__ linw,
    const float* __restrict__ inv_cnt, float* __restrict__ outg,
    int n_nodes, int do_pool)
{
    __shared__ float wsh[2][4096];   // 2 x 16 KB
    __shared__ float gacc[64][2];    // per-block graph partials (head fusion)
    int t = threadIdx.x;
    int gt = blockIdx.x * 256 + t;
    int g = gt >> 4, q = gt & 15;
    int n0 = g * 4;
    bool active = (n0 < n_nodes);

    {
        const float4* sp = (const float4*)wroot;
        float4* d = (float4*)wsh[0];
#pragma unroll
        for (int i = 0; i < 4; ++i) d[t + i * 256] = sp[t + i * 256];
    }

    float4 acc[4];
    float4 b = {0.f, 0.f, 0.f, 0.f};
    if (active) b = *(const float4*)(bias + q * 4);
#pragma unroll
    for (int i = 0; i < 4; ++i) acc[i] = b;

    const float* hv = hin + (size_t)n0 * 64;
    const float* mv = means + (size_t)n0 * 192;

    for (int s = 0; s < 4; ++s) {
        __syncthreads();
        if (s < 3) {
            const float4* sp = (const float4*)wrel + (size_t)s * 1024;
            float4* d = (float4*)wsh[(s + 1) & 1];
#pragma unroll
            for (int i = 0; i < 4; ++i) d[t + i * 256] = sp[t + i * 256];
        }
        const float* vbase = (s == 0) ? hv : (mv + (s - 1) * 64);
        int vstride = (s == 0) ? 64 : 192;
        const float* wbuf = wsh[s & 1];
        if (active) {
#pragma unroll 4
            for (int k4 = 0; k4 < 16; ++k4) {
                float4 v[4];
#pragma unroll
                for (int i = 0; i < 4; ++i)
                    v[i] = *(const float4*)(vbase + i * vstride + k4 * 4);
#pragma unroll
                for (int kk = 0; kk < 4; ++kk) {
                    float4 w = *(const float4*)(wbuf + (k4 * 4 + kk) * 64 + q * 4);
#pragma unroll
                    for (int i = 0; i < 4; ++i) {
                        float sv = kk == 0 ? v[i].x : kk == 1 ? v[i].y : kk == 2 ? v[i].z : v[i].w;
                        acc[i].x = fmaf(sv, w.x, acc[i].x);
                        acc[i].y = fmaf(sv, w.y, acc[i].y);
                        acc[i].z = fmaf(sv, w.z, acc[i].z);
                        acc[i].w = fmaf(sv, w.w, acc[i].w);
                    }
                }
            }
        }
    }
    if (!do_pool) {
        if (active) {
            float* o = hout + (size_t)n0 * 64 + q * 4;
#pragma unroll
            for (int i = 0; i < 4; ++i) {
                float4 r = {fmaxf(acc[i].x, 0.f), fmaxf(acc[i].y, 0.f),
                            fmaxf(acc[i].z, 0.f), fmaxf(acc[i].w, 0.f)};
                *(float4*)(o + i * 64) = r;
            }
        }
    } else {
        if (t < 64) { gacc[t][0] = 0.f; gacc[t][1] = 0.f; }
        __syncthreads();
        int nbase = blockIdx.x * 64;
        int gmin = batch[min(nbase, n_nodes - 1)];
        if (active) {
            float4 lwA = *(const float4*)(linw + q * 8);       // (c0w0,c0w1,c1w0,c1w1)
            float4 lwB = *(const float4*)(linw + q * 8 + 4);   // (c2w0,c2w1,c3w0,c3w1)
            float d0[4], d1[4];
#pragma unroll
            for (int i = 0; i < 4; ++i) {
                float4 r = {fmaxf(acc[i].x, 0.f), fmaxf(acc[i].y, 0.f),
                            fmaxf(acc[i].z, 0.f), fmaxf(acc[i].w, 0.f)};
                d0[i] = r.x * lwA.x + r.y * lwA.z + r.z * lwB.x + r.w * lwB.z;
                d1[i] = r.x * lwA.y + r.y * lwA.w + r.z * lwB.y + r.w * lwB.w;
            }
#pragma unroll
            for (int off = 1; off < 16; off <<= 1) {
#pragma unroll
                for (int i = 0; i < 4; ++i) {
                    d0[i] += __shfl_xor(d0[i], off);
                    d1[i] += __shfl_xor(d1[i], off);
                }
            }
            if (q == 0) {
#pragma unroll
                for (int i = 0; i < 4; ++i) {
                    int n = n0 + i;
                    if (n < n_nodes) {
                        int gg = batch[n];
                        float ic = inv_cnt[gg];
                        int idx = gg - gmin;
                        if (idx < 64) {
                            atomicAdd(&gacc[idx][0], d0[i] * ic);
                            atomicAdd(&gacc[idx][1], d1[i] * ic);
                        } else {   // empty-graph gap fallback (practically never)
                            atomicAdd(&outg[2 * gg + 0], d0[i] * ic);
                            atomicAdd(&outg[2 * gg + 1], d1[i] * ic);
                        }
                    }
                }
            }
        }
        __syncthreads();
        if (t < 64) {
            float v0 = gacc[t][0], v1 = gacc[t][1];
            if (v0 != 0.f || v1 != 0.f) {
                atomicAdd(&outg[2 * (gmin + t) + 0], v0);
                atomicAdd(&outg[2 * (gmin + t) + 1], v1);
            }
        }
    }
}

extern "C" void kernel_launch(void* const* d_in, const int* in_sizes, int n_in,
                              void* d_out, int out_size, void* d_ws, size_t ws_size,
                              hipStream_t stream)
{
    const int*   x      = (const int*)d_in[0];
    const int*   ei     = (const int*)d_in[1];
    const int*   et     = (const int*)d_in[2];
    const int*   batch  = (const int*)d_in[3];
    const float* emb    = (const float*)d_in[4];
    const float* w1rel  = (const float*)d_in[5];
    const float* w1root = (const float*)d_in[6];
    const float* b1     = (const float*)d_in[7];
    const float* w2rel  = (const float*)d_in[8];
    const float* w2root = (const float*)d_in[9];
    const float* b2     = (const float*)d_in[10];
    const float* linw   = (const float*)d_in[11];
    const float* linb   = (const float*)d_in[12];
    float* out = (float*)d_out;

    const int N = in_sizes[0];            // 50000
    const int E = in_sizes[2];            // 1250000
    const int G = out_size / 2;           // 512
    const int NBKT = (N + 127) >> 7;      // 391
    const int NCHK = (E + CHUNK - 1) / CHUNK;  // 611

    float* hA        = (float*)d_ws;                     // [N][64]
    float* hB        = hA + (size_t)N * 64;              // [N][64]
    float* means     = hB + (size_t)N * 64;              // [N][192]
    int*   esort     = (int*)(means + (size_t)N * 192);  // [E]
    int*   rowstartR = esort + E;                        // [4N+4]
    int*   bucket_start = rowstartR + 4 * N + 4;         // [NBKT+1]
    int*   totals    = bucket_start + NBKT + 1;          // [NBKT]
    float* inv_cnt   = (float*)(totals + NBKT);          // [G]
    int*   scratch   = (int*)means;                      // sort scratch (12.8 MB)
    int*   pcount    = (int*)means + 4 * 1024 * 1024;    // [NCHK*NBKT]
    int*   pre       = (int*)means + 5 * 1024 * 1024;    // [NCHK*NBKT]

    int embedBlocks = (N * 16 + 255) / 256;              // 3125
    embed_count_kernel<<<embedBlocks + NCHK, 256, 0, stream>>>(
        x, emb, hA, ei, pcount, N, E, NBKT, embedBlocks);
    int gBlocks = (G + 255) / 256;                       // graph-bounds tail blocks
    colscan_kernel<<<NBKT + gBlocks, 256, 0, stream>>>(
        pcount, pre, totals, rowstartR, batch, linb, inv_cnt, out,
        NCHK, NBKT, E, N, G);
    scatter_kernel<<<NCHK, 256, 0, stream>>>(ei, et, pre, totals, esort, bucket_start, E, NBKT);
    bucket_sort_kernel<<<NBKT, 256, 0, stream>>>(bucket_start, esort, scratch, rowstartR, N);

    int aggBlocks = (N * 64 + 255) / 256;                // one wave per dst
    int tfBlocks  = ((N + 3) / 4 * 16 + 255) / 256;      // 4 nodes per thread
    agg_kernel<<<aggBlocks, 256, 0, stream>>>(hA, rowstartR, esort, means, N);
    transform_kernel<<<tfBlocks, 256, 0, stream>>>(
        hA, means, w1root, w1rel, b1, hB, batch, linw, inv_cnt, out, N, 0);
    agg_kernel<<<aggBlocks, 256, 0, stream>>>(hB, rowstartR, esort, means, N);
    transform_kernel<<<tfBlocks, 256, 0, stream>>>(
        hB, means, w2root, w2rel, b2, hA, batch, linw, inv_cnt, out, N, 1);
}